// Round 6
// baseline (178.793 us; speedup 1.0000x reference)
//
#include <hip/hip_runtime.h>
#include <hip/hip_bf16.h>
#include <stdint.h>

#define T_ 4
#define B_ 16
#define C_ 256
#define N_ 1024
#define HEADS_ 8
#define HD_ 32

typedef unsigned long long u64;
typedef unsigned char u8;
typedef unsigned short u16;

// ---------- prep: fused weight transpose (wqkv[c][768], wtp[c][256]) + BN ----
__global__ __launch_bounds__(256) void prep_kernel(
    const float* __restrict__ qw, const float* __restrict__ kw,
    const float* __restrict__ vw, const float* __restrict__ pw,
    const float* __restrict__ qg, const float* __restrict__ qb2,
    const float* __restrict__ qmn, const float* __restrict__ qvr,
    const float* __restrict__ kg, const float* __restrict__ kb2,
    const float* __restrict__ kmn, const float* __restrict__ kvr,
    const float* __restrict__ vg, const float* __restrict__ vb2,
    const float* __restrict__ vmn, const float* __restrict__ vvr,
    const float* __restrict__ pg, const float* __restrict__ pb2,
    const float* __restrict__ pmn, const float* __restrict__ pvr,
    float* __restrict__ wqkv, float* __restrict__ wtp,
    float* __restrict__ bnt) {
  if (blockIdx.x < 256) {
    int c = blockIdx.x;
    int o = threadIdx.x;
    wqkv[c * 768 + o]       = qw[o * C_ + c];
    wqkv[c * 768 + 256 + o] = kw[o * C_ + c];
    wqkv[c * 768 + 512 + o] = vw[o * C_ + c];
    wtp[c * C_ + o]         = pw[o * C_ + c];
  } else {
    int c = threadIdx.x;
    float rs;
    rs = sqrtf(qvr[c] + 1e-5f);
    bnt[0 * C_ + c] = qg[c] / rs;
    bnt[1 * C_ + c] = qb2[c] - qmn[c] * qg[c] / rs;
    rs = sqrtf(kvr[c] + 1e-5f);
    bnt[2 * C_ + c] = kg[c] / rs;
    bnt[3 * C_ + c] = kb2[c] - kmn[c] * kg[c] / rs;
    rs = sqrtf(vvr[c] + 1e-5f);
    bnt[4 * C_ + c] = vg[c] / rs;
    bnt[5 * C_ + c] = vb2[c] - vmn[c] * vg[c] / rs;
    rs = sqrtf(pvr[c] + 1e-5f);
    bnt[6 * C_ + c] = pg[c] / rs;
    bnt[7 * C_ + c] = pb2[c] - pmn[c] * pg[c] / rs;
  }
}

// ---------- P0: shortcut LIF + pack active-channel lists per site ----------
__global__ __launch_bounds__(256) void lif_pack(const float* __restrict__ x,
                                                u8* __restrict__ lists,
                                                u16* __restrict__ cnts) {
  int b = blockIdx.x >> 5;          // 32 n-tiles of 32
  int n0 = (blockIdx.x & 31) << 5;
  int tid = threadIdx.x;
  int l = tid & 63, w = tid >> 6;
  __shared__ float tile[C_ * 33];
  __shared__ u64 lmask[4][32][4];   // [t][nn][word] = 4 KB
  float v[32];
#pragma unroll
  for (int i = 0; i < 32; i++) v[i] = 0.f;
  int c = (w << 6) + l;             // this thread's channel
  for (int t = 0; t < T_; t++) {
    __syncthreads();
    const float* xp = x + (((size_t)t * B_ + b) * C_) * N_ + n0;
    for (int idx = tid; idx < C_ * 32; idx += 256) {
      int cc = idx >> 5, nn = idx & 31;
      tile[cc * 33 + nn] = xp[(size_t)cc * N_ + nn];
    }
    __syncthreads();
#pragma unroll
    for (int nn = 0; nn < 32; nn++) {
      float xv = tile[c * 33 + nn];
      float h = v[nn] + (xv - v[nn]) * 0.5f;   // tau=2 exact halving
      bool s = h >= 1.0f;
      v[nn] = s ? 0.f : h;                     // hard reset, detach
      u64 bal = __ballot(s);
      if (l == nn) lmask[t][nn][w] = bal;
    }
  }
  __syncthreads();
  // pack phase: 128 sites (4t x 32nn), ascending channel order
  if (tid < 128) {
    int t = tid >> 5, nn = tid & 31;
    int n = n0 + nn;
    size_t site = ((size_t)t * B_ + b) * N_ + n;
    u8* lp = lists + (site << 8);
    int cnt = 0;
    u64 m;
    m = lmask[t][nn][0];
    while (m) { lp[cnt++] = (u8)__builtin_ctzll(m); m &= m - 1; }
    m = lmask[t][nn][1];
    while (m) { lp[cnt++] = (u8)(64 + __builtin_ctzll(m)); m &= m - 1; }
    m = lmask[t][nn][2];
    while (m) { lp[cnt++] = (u8)(128 + __builtin_ctzll(m)); m &= m - 1; }
    m = lmask[t][nn][3];
    while (m) { lp[cnt++] = (u8)(192 + __builtin_ctzll(m)); m &= m - 1; }
    cnts[site] = (u16)cnt;
  }
}

// ---------- P1: sparse q/k/v conv + BN + LIF (counted lists, float4) ----------
// grid = b(16) x nt(256 tiles of 4 n); 1 site per wave; lane l owns o=4l+j.
// mask word layout (qm / kvw / vb): word j, bit l <-> channel c = 4l + j.
__global__ __launch_bounds__(256) void qkv_sparse(
    const u8* __restrict__ lists, const u16* __restrict__ cnts,
    const float* __restrict__ wqkv, const float* __restrict__ bnt,
    u8* __restrict__ pkvb, u64* __restrict__ qm_out,
    float* __restrict__ vout) {
  int b = blockIdx.x >> 8;
  int nt = blockIdx.x & 255;
  int n0 = nt << 2;
  int tid = threadIdx.x;
  int l = tid & 63, wv = tid >> 6;
  int n = n0 + wv;

  __shared__ u64 kvw[4][4][4];   // [nn][t][j] k&v spike words
  __shared__ u64 vb[4][4][4];    // [nn][t][j] v spike words

  float qsc[4], qsh[4], ksc[4], ksh[4], vsc[4], vsh[4];
#pragma unroll
  for (int j = 0; j < 4; j++) {
    int o = (l << 2) + j;
    qsc[j] = bnt[0 * C_ + o]; qsh[j] = bnt[1 * C_ + o];
    ksc[j] = bnt[2 * C_ + o]; ksh[j] = bnt[3 * C_ + o];
    vsc[j] = bnt[4 * C_ + o]; vsh[j] = bnt[5 * C_ + o];
  }
  float vq[4] = {0.f, 0.f, 0.f, 0.f};
  float vk[4] = {0.f, 0.f, 0.f, 0.f};
  float vv2[4] = {0.f, 0.f, 0.f, 0.f};

  for (int t = 0; t < 4; t++) {
    size_t site = ((size_t)t * B_ + b) * N_ + n;
    const u8* lp = lists + (site << 8);
    int cn = cnts[site];
    float aq[4] = {0.f, 0.f, 0.f, 0.f};
    float ak[4] = {0.f, 0.f, 0.f, 0.f};
    float av[4] = {0.f, 0.f, 0.f, 0.f};
    if (cn > 0) {
      int ca = lp[0];
      const float4* pa = (const float4*)(wqkv + ca * 768) + l;
      float4 q0 = pa[0], k0 = pa[64], v0 = pa[128];
      for (int i = 1; i < cn; i++) {
        int cb = lp[i];
        const float4* pb = (const float4*)(wqkv + cb * 768) + l;
        float4 q1 = pb[0], k1 = pb[64], v1 = pb[128];
        aq[0] += q0.x; aq[1] += q0.y; aq[2] += q0.z; aq[3] += q0.w;
        ak[0] += k0.x; ak[1] += k0.y; ak[2] += k0.z; ak[3] += k0.w;
        av[0] += v0.x; av[1] += v0.y; av[2] += v0.z; av[3] += v0.w;
        q0 = q1; k0 = k1; v0 = v1;
      }
      aq[0] += q0.x; aq[1] += q0.y; aq[2] += q0.z; aq[3] += q0.w;
      ak[0] += k0.x; ak[1] += k0.y; ak[2] += k0.z; ak[3] += k0.w;
      av[0] += v0.x; av[1] += v0.y; av[2] += v0.z; av[3] += v0.w;
    }
    // BN + LIF step for this t
#pragma unroll
    for (int j = 0; j < 4; j++) {
      float pq = aq[j] * qsc[j] + qsh[j];
      float pk = ak[j] * ksc[j] + ksh[j];
      float pv = av[j] * vsc[j] + vsh[j];
      float hq = vq[j] + (pq - vq[j]) * 0.5f;
      float hk = vk[j] + (pk - vk[j]) * 0.5f;
      float hv = vv2[j] + (pv - vv2[j]) * 0.5f;
      bool sq = hq >= 1.0f; vq[j] = sq ? 0.f : hq;
      bool sk = hk >= 1.0f; vk[j] = sk ? 0.f : hk;
      bool sv = hv >= 1.0f; vv2[j] = sv ? 0.f : hv;
      u64 bq = __ballot(sq);
      u64 bkv = __ballot(sk && sv);
      u64 bv = __ballot(sv);
      if (l == (t << 2) + j) {
        qm_out[(site << 2) + j] = bq;
        kvw[wv][t][j] = bkv;
        vb[wv][t][j] = bv;
      }
    }
  }
  __syncthreads();

  // pkv partial-count write: per (t, c) count over the block's 4 sites
#pragma unroll
  for (int t = 0; t < 4; t++) {
    int c = tid;
    int ll = c >> 2, j = c & 3;
    int s = (int)((kvw[0][t][j] >> ll) & 1ull) +
            (int)((kvw[1][t][j] >> ll) & 1ull) +
            (int)((kvw[2][t][j] >> ll) & 1ull) +
            (int)((kvw[3][t][j] >> ll) & 1ull);
    pkvb[((((size_t)t * B_ + b) * C_ + c) << 8) + nt] = (u8)s;
  }

  // coalesced vout write phase: 32 (t,head) spans of 128 contiguous floats
  {
    int th = tid >> 3;          // 0..31
    int t = th >> 3;            // 0..3
    int head = th & 7;
    int part = tid & 7;
    int nn = part >> 1;
    int e0 = part << 4;         // 16 elements per thread
    float* vp = vout +
        ((((size_t)t * B_ + b) * HEADS_ + head) * N_ + n0) * HD_ + e0;
#pragma unroll
    for (int f = 0; f < 4; f++) {
      int e = e0 + (f << 2);
      int hd = e & 31;
      int li = (head << 3) + (hd >> 2);
      float4 o4;
      o4.x = ((vb[nn][t][0] >> li) & 1ull) ? 1.f : 0.f;
      o4.y = ((vb[nn][t][1] >> li) & 1ull) ? 1.f : 0.f;
      o4.z = ((vb[nn][t][2] >> li) & 1ull) ? 1.f : 0.f;
      o4.w = ((vb[nn][t][3] >> li) & 1ull) ? 1.f : 0.f;
      *(float4*)(vp + (f << 2)) = o4;
    }
  }
}

// ---------- P2: reduce kv partials + talking-heads LIF (v_th=0.5) ----------
// wave j, lane l -> channel c = 4l + j; ballot word matches qm layout.
__global__ __launch_bounds__(256) void kv_lif_kernel(const u8* __restrict__ pkvb,
                                                     u64* __restrict__ kvsm) {
  int b = blockIdx.x;
  int tid = threadIdx.x;
  int l = tid & 63, j = tid >> 6;
  int c = (l << 2) + j;
  float v = 0.f;
  for (int t = 0; t < 4; t++) {
    const uint4* p =
        (const uint4*)(pkvb + ((((size_t)t * B_ + b) * C_ + c) << 8));
    int s = 0;
    for (int i = 0; i < 16; i++) {
      uint4 u = p[i];
      unsigned a;
      a = u.x; s += (a & 255) + ((a >> 8) & 255) + ((a >> 16) & 255) + (a >> 24);
      a = u.y; s += (a & 255) + ((a >> 8) & 255) + ((a >> 16) & 255) + (a >> 24);
      a = u.z; s += (a & 255) + ((a >> 8) & 255) + ((a >> 16) & 255) + (a >> 24);
      a = u.w; s += (a & 255) + ((a >> 8) & 255) + ((a >> 16) & 255) + (a >> 24);
    }
    float kvs = (float)s;                    // exact integer
    float h = v + (kvs - v) * 0.5f;
    bool sp = h >= 0.5f;
    v = sp ? 0.f : h;
    u64 bal = __ballot(sp);
    if (l == t) kvsm[((size_t)t * B_ + b) * 4 + j] = bal;
  }
}

// ---------- P3: attn = q & kvs -> sparse proj + bias + BN + identity ----------
__global__ __launch_bounds__(256) void proj_sparse(
    const u64* __restrict__ qm, const u64* __restrict__ kvsm,
    const float* __restrict__ wtp, const float* __restrict__ bnt,
    const float* __restrict__ pbias, const float* __restrict__ x,
    float* __restrict__ out) {
  int tb = blockIdx.x >> 5;         // 64 (t,b) x 32 n-tiles of 32
  int n0 = (blockIdx.x & 31) << 5;
  int t = tb >> 4, b = tb & 15;
  int tid = threadIdx.x;
  int l = tid & 63, w = tid >> 6;
  __shared__ float tile[C_ * 33];
  u64 kvm[4];
#pragma unroll
  for (int j = 0; j < 4; j++) kvm[j] = kvsm[((size_t)t * B_ + b) * 4 + j];
  for (int nn = w; nn < 32; nn += 4) {
    int n = n0 + nn;
    float acc[4] = {0.f, 0.f, 0.f, 0.f};
    size_t site = ((size_t)t * B_ + b) * N_ + n;
    const u64* mp = qm + (site << 2);
#pragma unroll
    for (int j = 0; j < 4; j++) {
      u64 m = mp[j] & kvm[j];
      while (m) {
        int li = __builtin_ctzll(m);
        m &= m - 1;
        int c = (li << 2) + j;    // c = 4*bit + j layout
        const float* rp = wtp + c * C_;
#pragma unroll
        for (int jj = 0; jj < 4; jj++) acc[jj] += rp[(jj << 6) + l];
      }
    }
#pragma unroll
    for (int jj = 0; jj < 4; jj++) tile[((jj << 6) + l) * 33 + nn] = acc[jj];
  }
  __syncthreads();
  // per-row epilogue, coalesced over n (verified round-4/5 math)
  int col = l & 31;
  int half = l >> 5;
  for (int r = (w << 1) + half; r < C_; r += 8) {
    float val = tile[r * 33 + col];
    float z = (val + pbias[r]) * bnt[6 * C_ + r] + bnt[7 * C_ + r];
    size_t xi = (((size_t)t * B_ + b) * C_ + r) * N_ + n0 + col;
    out[xi] = z + x[xi];
  }
}

// ---------- diagnostic: if ws too small, zero the output ----------
__global__ __launch_bounds__(256) void fill_zero_f32(float* p, size_t n) {
  size_t i = (size_t)blockIdx.x * 256 + threadIdx.x;
  if (i < n) p[i] = 0.0f;
}

extern "C" void kernel_launch(void* const* d_in, const int* in_sizes, int n_in,
                              void* d_out, int out_size, void* d_ws, size_t ws_size,
                              hipStream_t stream) {
  const float* x  = (const float*)d_in[0];
  const float* qw = (const float*)d_in[1];
  const float* qg = (const float*)d_in[2];
  const float* qb = (const float*)d_in[3];
  const float* qm = (const float*)d_in[4];
  const float* qv = (const float*)d_in[5];
  const float* kw = (const float*)d_in[6];
  const float* kg = (const float*)d_in[7];
  const float* kb = (const float*)d_in[8];
  const float* km = (const float*)d_in[9];
  const float* kv = (const float*)d_in[10];
  const float* vw = (const float*)d_in[11];
  const float* vg = (const float*)d_in[12];
  const float* vb2 = (const float*)d_in[13];
  const float* vm = (const float*)d_in[14];
  const float* vv = (const float*)d_in[15];
  const float* pw = (const float*)d_in[16];
  const float* pbias = (const float*)d_in[17];
  const float* pg = (const float*)d_in[18];
  const float* pb = (const float*)d_in[19];
  const float* pm = (const float*)d_in[20];
  const float* pv = (const float*)d_in[21];

  const size_t needed = 24258560ull;   // ~24.3 MB (ws proven >= 43 MB in r2)
  if (ws_size < needed) {
    size_t n = (size_t)out_size;
    fill_zero_f32<<<(unsigned)((n + 255) / 256), 256, 0, stream>>>(
        (float*)d_out, n);
    return;
  }

  char* ws = (char*)d_ws;
  float* wqkv  = (float*)(ws + 0);         // 768 KB  [c][q|k|v 256 each]
  float* wtp   = (float*)(ws + 786432);    // 256 KB  [c][o]
  float* bnt   = (float*)(ws + 1048576);   // 8 KB
  u8*    lists = (u8*)   (ws + 1056768);   // 16 MB   [site][256]
  u16*   cnts  = (u16*)  (ws + 17833984);  // 128 KB  [site]
  u64*   qmm   = (u64*)  (ws + 17965056);  // 2 MB    [site][4 j-words]
  u8*    pkvb  = (u8*)   (ws + 20062208);  // 4 MB    [t][b][c][256 tiles]
  u64*   kvsm  = (u64*)  (ws + 24256512);  // 2 KB    [t][b][4 j-words]

  float* out  = (float*)d_out;
  float* vout = out + (size_t)T_ * B_ * C_ * N_;

  prep_kernel<<<257, 256, 0, stream>>>(qw, kw, vw, pw,
                                       qg, qb, qm, qv, kg, kb, km, kv,
                                       vg, vb2, vm, vv, pg, pb, pm, pv,
                                       wqkv, wtp, bnt);
  lif_pack<<<512, 256, 0, stream>>>(x, lists, cnts);
  qkv_sparse<<<4096, 256, 0, stream>>>(lists, cnts, wqkv, bnt, pkvb, qmm, vout);
  kv_lif_kernel<<<16, 256, 0, stream>>>(pkvb, kvsm);
  proj_sparse<<<2048, 256, 0, stream>>>(qmm, kvsm, wtp, bnt, pbias, x, out);
}

// Round 7
// 157.617 us; speedup vs baseline: 1.1344x; 1.1344x over previous
//
#include <hip/hip_runtime.h>
#include <hip/hip_bf16.h>
#include <stdint.h>

#define T_ 4
#define B_ 16
#define C_ 256
#define N_ 1024
#define HEADS_ 8
#define HD_ 32

typedef unsigned long long u64;
typedef unsigned char u8;

__device__ __forceinline__ u64 rf64(u64 v) {
  unsigned lo = __builtin_amdgcn_readfirstlane((unsigned)v);
  unsigned hi = __builtin_amdgcn_readfirstlane((unsigned)(v >> 32));
  return ((u64)hi << 32) | (u64)lo;
}

// ---------- prep: fused weight transpose (wqkv[c][768], wtp[c][256]) + BN ----
__global__ __launch_bounds__(256) void prep_kernel(
    const float* __restrict__ qw, const float* __restrict__ kw,
    const float* __restrict__ vw, const float* __restrict__ pw,
    const float* __restrict__ qg, const float* __restrict__ qb2,
    const float* __restrict__ qmn, const float* __restrict__ qvr,
    const float* __restrict__ kg, const float* __restrict__ kb2,
    const float* __restrict__ kmn, const float* __restrict__ kvr,
    const float* __restrict__ vg, const float* __restrict__ vb2,
    const float* __restrict__ vmn, const float* __restrict__ vvr,
    const float* __restrict__ pg, const float* __restrict__ pb2,
    const float* __restrict__ pmn, const float* __restrict__ pvr,
    float* __restrict__ wqkv, float* __restrict__ wtp,
    float* __restrict__ bnt) {
  if (blockIdx.x < 256) {
    int c = blockIdx.x;
    int o = threadIdx.x;
    wqkv[c * 768 + o]       = qw[o * C_ + c];
    wqkv[c * 768 + 256 + o] = kw[o * C_ + c];
    wqkv[c * 768 + 512 + o] = vw[o * C_ + c];
    wtp[c * C_ + o]         = pw[o * C_ + c];
  } else {
    int c = threadIdx.x;
    float rs;
    rs = sqrtf(qvr[c] + 1e-5f);
    bnt[0 * C_ + c] = qg[c] / rs;
    bnt[1 * C_ + c] = qb2[c] - qmn[c] * qg[c] / rs;
    rs = sqrtf(kvr[c] + 1e-5f);
    bnt[2 * C_ + c] = kg[c] / rs;
    bnt[3 * C_ + c] = kb2[c] - kmn[c] * kg[c] / rs;
    rs = sqrtf(vvr[c] + 1e-5f);
    bnt[4 * C_ + c] = vg[c] / rs;
    bnt[5 * C_ + c] = vb2[c] - vmn[c] * vg[c] / rs;
    rs = sqrtf(pvr[c] + 1e-5f);
    bnt[6 * C_ + c] = pg[c] / rs;
    bnt[7 * C_ + c] = pb2[c] - pmn[c] * pg[c] / rs;
  }
}

// ---------- P0: shortcut LIF -> xs bitmasks [site][4 words], c = 64w + l ----
__global__ __launch_bounds__(256) void lif_shortcut(const float* __restrict__ x,
                                                    u64* __restrict__ xsm) {
  int b = blockIdx.x >> 5;          // 32 n-tiles of 32
  int n0 = (blockIdx.x & 31) << 5;
  int tid = threadIdx.x;
  int l = tid & 63, w = tid >> 6;
  __shared__ float tile[C_ * 33];
  float v[32];
#pragma unroll
  for (int i = 0; i < 32; i++) v[i] = 0.f;
  int c = (w << 6) + l;             // this thread's channel
  for (int t = 0; t < T_; t++) {
    __syncthreads();
    const float* xp = x + (((size_t)t * B_ + b) * C_) * N_ + n0;
    for (int idx = tid; idx < C_ * 32; idx += 256) {
      int cc = idx >> 5, nn = idx & 31;
      tile[cc * 33 + nn] = xp[(size_t)cc * N_ + nn];
    }
    __syncthreads();
#pragma unroll
    for (int nn = 0; nn < 32; nn++) {
      float xv = tile[c * 33 + nn];
      float h = v[nn] + (xv - v[nn]) * 0.5f;   // tau=2 exact halving
      bool s = h >= 1.0f;
      v[nn] = s ? 0.f : h;                     // hard reset, detach
      u64 bal = __ballot(s);
      if (l == nn) xsm[(((size_t)t * B_ + b) * N_ + n0 + nn) * 4 + w] = bal;
    }
  }
}

// ---------- P1: sparse q/k/v conv + BN + LIF ----------
// grid = b(16) x nt(128 tiles of 8 n); wave wv owns sites n0+wv, n0+wv+4.
// lane l owns out-channels o = 4l+j; ballot word j, bit l <-> c = 4l+j.
// SALU mask walk (readfirstlane) + float4 loads pipelined 1-deep.
__global__ __launch_bounds__(256) void qkv_sparse(
    const u64* __restrict__ xsm, const float* __restrict__ wqkv,
    const float* __restrict__ bnt, u8* __restrict__ pkvb,
    u64* __restrict__ qm_out, float* __restrict__ vout) {
  int b = blockIdx.x >> 7;
  int nt = blockIdx.x & 127;
  int n0 = nt << 3;
  int tid = threadIdx.x;
  int l = tid & 63, wv = tid >> 6;

  __shared__ u64 kvw[8][4][4];   // [nn][t][j] k&v spike words
  __shared__ u64 vb[8][4][4];    // [nn][t][j] v spike words

  float qsc[4], qsh[4], ksc[4], ksh[4], vsc[4], vsh[4];
#pragma unroll
  for (int j = 0; j < 4; j++) {
    int o = (l << 2) + j;
    qsc[j] = bnt[0 * C_ + o]; qsh[j] = bnt[1 * C_ + o];
    ksc[j] = bnt[2 * C_ + o]; ksh[j] = bnt[3 * C_ + o];
    vsc[j] = bnt[4 * C_ + o]; vsh[j] = bnt[5 * C_ + o];
  }

  for (int s = 0; s < 2; s++) {
    int nn = wv + (s << 2);        // site index in block, 0..7
    int n = n0 + nn;
    float vq[4] = {0.f, 0.f, 0.f, 0.f};
    float vk[4] = {0.f, 0.f, 0.f, 0.f};
    float vv2[4] = {0.f, 0.f, 0.f, 0.f};
#pragma unroll
    for (int t = 0; t < 4; t++) {
      size_t site = ((size_t)t * B_ + b) * N_ + n;
      const u64* mp = xsm + (site << 2);
      float aq[4] = {0.f, 0.f, 0.f, 0.f};
      float ak[4] = {0.f, 0.f, 0.f, 0.f};
      float av[4] = {0.f, 0.f, 0.f, 0.f};
      // zero-seeded 1-deep pipeline: first accumulate adds exact zeros
      float4 q0 = {0.f, 0.f, 0.f, 0.f};
      float4 k0 = {0.f, 0.f, 0.f, 0.f};
      float4 v0 = {0.f, 0.f, 0.f, 0.f};
#pragma unroll
      for (int wd = 0; wd < 4; wd++) {
        u64 m = rf64(mp[wd]);            // SGPR-resident mask walk
        while (m) {
          int c = (wd << 6) + __builtin_ctzll(m);
          m &= m - 1;
          const float4* pb = (const float4*)(wqkv + c * 768) + l;
          float4 q1 = pb[0];
          float4 k1 = pb[64];
          float4 v1 = pb[128];
          aq[0] += q0.x; aq[1] += q0.y; aq[2] += q0.z; aq[3] += q0.w;
          ak[0] += k0.x; ak[1] += k0.y; ak[2] += k0.z; ak[3] += k0.w;
          av[0] += v0.x; av[1] += v0.y; av[2] += v0.z; av[3] += v0.w;
          q0 = q1; k0 = k1; v0 = v1;
        }
      }
      aq[0] += q0.x; aq[1] += q0.y; aq[2] += q0.z; aq[3] += q0.w;
      ak[0] += k0.x; ak[1] += k0.y; ak[2] += k0.z; ak[3] += k0.w;
      av[0] += v0.x; av[1] += v0.y; av[2] += v0.z; av[3] += v0.w;
      // BN + LIF step for this t
#pragma unroll
      for (int j = 0; j < 4; j++) {
        float pq = aq[j] * qsc[j] + qsh[j];
        float pk = ak[j] * ksc[j] + ksh[j];
        float pv = av[j] * vsc[j] + vsh[j];
        float hq = vq[j] + (pq - vq[j]) * 0.5f;
        float hk = vk[j] + (pk - vk[j]) * 0.5f;
        float hv = vv2[j] + (pv - vv2[j]) * 0.5f;
        bool sq = hq >= 1.0f; vq[j] = sq ? 0.f : hq;
        bool sk = hk >= 1.0f; vk[j] = sk ? 0.f : hk;
        bool sv = hv >= 1.0f; vv2[j] = sv ? 0.f : hv;
        u64 bq = __ballot(sq);
        u64 bkv = __ballot(sk && sv);
        u64 bv = __ballot(sv);
        if (l == (t << 2) + j) {
          qm_out[(site << 2) + j] = bq;
          kvw[nn][t][j] = bkv;
          vb[nn][t][j] = bv;
        }
      }
    }
  }
  __syncthreads();

  // pkv partial-count write: per (t,c), count over the block's 8 sites
#pragma unroll
  for (int t = 0; t < 4; t++) {
    int c = tid;
    int ll = c >> 2, j = c & 3;
    int ssum = 0;
#pragma unroll
    for (int s8 = 0; s8 < 8; s8++)
      ssum += (int)((kvw[s8][t][j] >> ll) & 1ull);
    pkvb[((((size_t)t * B_ + b) * C_ + c) << 7) + nt] = (u8)ssum;
  }

  // coalesced vout write: 32 (t,head) groups x 8 threads; one n_local each
  {
    int th = tid >> 3;          // 0..31
    int t = th >> 3;            // 0..3
    int head = th & 7;
    int nl = tid & 7;           // n_local 0..7
    float* vp = vout +
        ((((size_t)t * B_ + b) * HEADS_ + head) * N_ + n0 + nl) * HD_;
#pragma unroll
    for (int m4 = 0; m4 < 8; m4++) {     // hd = 4*m4
      int li = (head << 3) + m4;         // c>>2 for c = head*32 + 4*m4 + e
      float4 o4;
      o4.x = ((vb[nl][t][0] >> li) & 1ull) ? 1.f : 0.f;
      o4.y = ((vb[nl][t][1] >> li) & 1ull) ? 1.f : 0.f;
      o4.z = ((vb[nl][t][2] >> li) & 1ull) ? 1.f : 0.f;
      o4.w = ((vb[nl][t][3] >> li) & 1ull) ? 1.f : 0.f;
      *(float4*)(vp + (m4 << 2)) = o4;
    }
  }
}

// ---------- P2: reduce kv partials + talking-heads LIF (v_th=0.5) ----------
// wave j, lane l -> channel c = 4l + j; ballot word matches qm layout.
__global__ __launch_bounds__(256) void kv_lif_kernel(const u8* __restrict__ pkvb,
                                                     u64* __restrict__ kvsm) {
  int b = blockIdx.x;
  int tid = threadIdx.x;
  int l = tid & 63, j = tid >> 6;
  int c = (l << 2) + j;
  float v = 0.f;
  for (int t = 0; t < 4; t++) {
    const uint4* p =
        (const uint4*)(pkvb + ((((size_t)t * B_ + b) * C_ + c) << 7));
    int s = 0;
#pragma unroll
    for (int i = 0; i < 8; i++) {
      uint4 u = p[i];
      unsigned a;
      a = u.x; s += (a & 255) + ((a >> 8) & 255) + ((a >> 16) & 255) + (a >> 24);
      a = u.y; s += (a & 255) + ((a >> 8) & 255) + ((a >> 16) & 255) + (a >> 24);
      a = u.z; s += (a & 255) + ((a >> 8) & 255) + ((a >> 16) & 255) + (a >> 24);
      a = u.w; s += (a & 255) + ((a >> 8) & 255) + ((a >> 16) & 255) + (a >> 24);
    }
    float kvs = (float)s;                    // exact integer
    float h = v + (kvs - v) * 0.5f;
    bool sp = h >= 0.5f;
    v = sp ? 0.f : h;
    u64 bal = __ballot(sp);
    if (l == t) kvsm[((size_t)t * B_ + b) * 4 + j] = bal;
  }
}

// ---------- P3: attn = q & kvs -> sparse proj + bias + BN + identity ----------
__global__ __launch_bounds__(256) void proj_sparse(
    const u64* __restrict__ qm, const u64* __restrict__ kvsm,
    const float* __restrict__ wtp, const float* __restrict__ bnt,
    const float* __restrict__ pbias, const float* __restrict__ x,
    float* __restrict__ out) {
  int tb = blockIdx.x >> 5;         // 64 (t,b) x 32 n-tiles of 32
  int n0 = (blockIdx.x & 31) << 5;
  int t = tb >> 4, b = tb & 15;
  int tid = threadIdx.x;
  int l = tid & 63, w = tid >> 6;
  __shared__ float tile[C_ * 33];
  u64 kvm[4];
#pragma unroll
  for (int j = 0; j < 4; j++) kvm[j] = kvsm[((size_t)t * B_ + b) * 4 + j];
  for (int nn = w; nn < 32; nn += 4) {
    int n = n0 + nn;
    float acc[4] = {0.f, 0.f, 0.f, 0.f};
    size_t site = ((size_t)t * B_ + b) * N_ + n;
    const u64* mp = qm + (site << 2);
#pragma unroll
    for (int j = 0; j < 4; j++) {
      u64 m = rf64(mp[j]) & kvm[j];
      while (m) {
        int li = __builtin_ctzll(m);
        m &= m - 1;
        int c = (li << 2) + j;    // c = 4*bit + j layout
        const float* rp = wtp + c * C_;
#pragma unroll
        for (int jj = 0; jj < 4; jj++) acc[jj] += rp[(jj << 6) + l];
      }
    }
#pragma unroll
    for (int jj = 0; jj < 4; jj++) tile[((jj << 6) + l) * 33 + nn] = acc[jj];
  }
  __syncthreads();
  // per-row epilogue, coalesced over n (verified round-4/5/6 math)
  int col = l & 31;
  int half = l >> 5;
  for (int r = (w << 1) + half; r < C_; r += 8) {
    float val = tile[r * 33 + col];
    float z = (val + pbias[r]) * bnt[6 * C_ + r] + bnt[7 * C_ + r];
    size_t xi = (((size_t)t * B_ + b) * C_ + r) * N_ + n0 + col;
    out[xi] = z + x[xi];
  }
}

// ---------- diagnostic: if ws too small, zero the output ----------
__global__ __launch_bounds__(256) void fill_zero_f32(float* p, size_t n) {
  size_t i = (size_t)blockIdx.x * 256 + threadIdx.x;
  if (i < n) p[i] = 0.0f;
}

extern "C" void kernel_launch(void* const* d_in, const int* in_sizes, int n_in,
                              void* d_out, int out_size, void* d_ws, size_t ws_size,
                              hipStream_t stream) {
  const float* x  = (const float*)d_in[0];
  const float* qw = (const float*)d_in[1];
  const float* qg = (const float*)d_in[2];
  const float* qb = (const float*)d_in[3];
  const float* qm = (const float*)d_in[4];
  const float* qv = (const float*)d_in[5];
  const float* kw = (const float*)d_in[6];
  const float* kg = (const float*)d_in[7];
  const float* kb = (const float*)d_in[8];
  const float* km = (const float*)d_in[9];
  const float* kv = (const float*)d_in[10];
  const float* vw = (const float*)d_in[11];
  const float* vg = (const float*)d_in[12];
  const float* vb2 = (const float*)d_in[13];
  const float* vm = (const float*)d_in[14];
  const float* vv = (const float*)d_in[15];
  const float* pw = (const float*)d_in[16];
  const float* pbias = (const float*)d_in[17];
  const float* pg = (const float*)d_in[18];
  const float* pb = (const float*)d_in[19];
  const float* pm = (const float*)d_in[20];
  const float* pv = (const float*)d_in[21];

  const size_t needed = 7342080ull + 2048ull;   // ~7.3 MB
  if (ws_size < needed) {
    size_t n = (size_t)out_size;
    fill_zero_f32<<<(unsigned)((n + 255) / 256), 256, 0, stream>>>(
        (float*)d_out, n);
    return;
  }

  char* ws = (char*)d_ws;
  float* wqkv = (float*)(ws + 0);         // 768 KB  [c][q|k|v 256 each]
  float* wtp  = (float*)(ws + 786432);    // 256 KB  [c][o]
  float* bnt  = (float*)(ws + 1048576);   // 8 KB
  u64*   xsm  = (u64*)  (ws + 1056768);   // 2 MB  [site][4 words], c = 64w+l
  u64*   qmm  = (u64*)  (ws + 3153920);   // 2 MB  [site][4 j-words], c = 4l+j
  u8*    pkvb = (u8*)   (ws + 5251072);   // 2 MB  [t][b][c][128 tiles]
  u64*   kvsm = (u64*)  (ws + 7348224);   // 2 KB  [t][b][4 j-words]

  float* out  = (float*)d_out;
  float* vout = out + (size_t)T_ * B_ * C_ * N_;

  prep_kernel<<<257, 256, 0, stream>>>(qw, kw, vw, pw,
                                       qg, qb, qm, qv, kg, kb, km, kv,
                                       vg, vb2, vm, vv, pg, pb, pm, pv,
                                       wqkv, wtp, bnt);
  lif_shortcut<<<512, 256, 0, stream>>>(x, xsm);
  qkv_sparse<<<2048, 256, 0, stream>>>(xsm, wqkv, bnt, pkvb, qmm, vout);
  kv_lif_kernel<<<16, 256, 0, stream>>>(pkvb, kvsm);
  proj_sparse<<<2048, 256, 0, stream>>>(qmm, kvsm, wtp, bnt, pbias, x, out);
}